// Round 1
// baseline (430.956 us; speedup 1.0000x reference)
//
#include <hip/hip_runtime.h>

// DySample fused kernel for MI355X (gfx950).
// x: [16,64,128,128] f32, w_off: [32,64] f32, b_off: [32] f32
// out: [16,64,256,256] f32
//
// Derivation (matches reference exactly up to benign fp reassociation):
//   offset[b,o,h,w] = (sum_c x[b,c,h,w]*w_off[o,c] + b_off[o]) * 0.25 + init(o)
//   output pixel (b, g*16+c, 2h+r1, 2w+r2):
//     q = g*4 + 2*r1 + r2
//     offx = offset channel q, offy = offset channel 16+q
//     init_x = init_y = ((g&1) ? r1 : r2) ? +0.25 : -0.25   (torch .repeat quirk)
//     ix = clip(w + offx, 0, 127); iy = clip(h + offy, 0, 127)
//     bilinear-sample x[b, g*16+c] at (iy, ix), border-clamped x1/y1.

namespace {
constexpr int BB = 16;
constexpr int CC = 64;
constexpr int HH = 128;
constexpr int WW = 128;
constexpr int HW = HH * WW;     // 16384
constexpr int OW = 2 * WW;      // 256
constexpr int OHW = 4 * HW;     // 65536
constexpr int TH = 8, TW = 32;  // input tile per block (256 threads, 1 px/thread)
constexpr int TILES = (HH / TH) * (WW / TW);  // 64
}

__global__ __launch_bounds__(256, 4)
void dysample_kernel(const float* __restrict__ x,
                     const float* __restrict__ w_off,
                     const float* __restrict__ b_off,
                     float* __restrict__ out) {
    __shared__ float2 coords[16][256];   // 32 KB: (ix,iy) per q per tile pixel

    const int tid  = threadIdx.x;
    const int b    = blockIdx.x >> 6;
    const int tile = blockIdx.x & 63;
    const int th0  = (tile >> 2) * TH;   // input-row base of tile
    const int tw0  = (tile & 3) * TW;    // input-col base of tile
    const int ty   = tid >> 5;           // [0,8)
    const int tx   = tid & 31;           // [0,32)
    const int h    = th0 + ty;
    const int w    = tw0 + tx;

    // ---------- Phase 1: 1x1 conv, 32 outputs at this thread's pixel ----------
    float acc[32];
#pragma unroll
    for (int o = 0; o < 32; ++o) acc[o] = b_off[o];

    const float* xb = x + b * (CC * HW) + h * WW + w;
#pragma unroll
    for (int half = 0; half < 2; ++half) {
        float xv[32];
#pragma unroll
        for (int c = 0; c < 32; ++c) xv[c] = xb[(half * 32 + c) * HW];
#pragma unroll
        for (int o = 0; o < 32; ++o) {
            float a = acc[o];
#pragma unroll
            for (int c = 0; c < 32; ++c)
                a = fmaf(xv[c], w_off[o * 64 + half * 32 + c], a);  // uniform -> s_load
            acc[o] = a;
        }
    }

    const float fw = (float)w, fh = (float)h;
#pragma unroll
    for (int q = 0; q < 16; ++q) {
        const int g = q >> 2, r1 = (q >> 1) & 1, r2 = q & 1;
        const float init = (((g & 1) ? r1 : r2) ? 0.25f : -0.25f);
        const float offx = fmaf(acc[q],      0.25f, init);
        const float offy = fmaf(acc[q + 16], 0.25f, init);
        // reproduce reference rounding: ((w+0.5)+off) - 0.5, then clip
        float ix = ((fw + 0.5f) + offx) - 0.5f;
        float iy = ((fh + 0.5f) + offy) - 0.5f;
        ix = fminf(fmaxf(ix, 0.0f), (float)(WW - 1));
        iy = fminf(fmaxf(iy, 0.0f), (float)(HH - 1));
        coords[q][tid] = make_float2(ix, iy);
    }
    __syncthreads();

    // ---------- Phase 2: bilinear sampling, 256 outputs per thread ----------
    for (int g = 0; g < 4; ++g) {
        const float* xg = x + (b * CC + g * 16) * HW;
        float* og = out + (size_t)(b * CC + g * 16) * OHW;
#pragma unroll
        for (int rep = 0; rep < 4; ++rep) {
            const int p  = rep * 256 + tid;    // [0,1024): output tile pixel
            const int oy = p >> 6;             // [0,16)
            const int ox = p & 63;             // [0,64)  -> coalesced stores
            const int q   = (g << 2) | ((oy & 1) << 1) | (ox & 1);
            const int pix = ((oy >> 1) << 5) | (ox >> 1);
            const float2 cc = coords[q][pix];
            const float x0f = floorf(cc.x), y0f = floorf(cc.y);
            const float wx = cc.x - x0f, wy = cc.y - y0f;
            const int x0 = (int)x0f, y0 = (int)y0f;
            const int x1 = min(x0 + 1, WW - 1);
            const int y1 = min(y0 + 1, HH - 1);
            const int o00 = y0 * WW + x0;
            const int o01 = y0 * WW + x1;
            const int o10 = y1 * WW + x0;
            const int o11 = y1 * WW + x1;
            const int oidx = (th0 * 2 + oy) * OW + (tw0 * 2 + ox);
#pragma unroll
            for (int c = 0; c < 16; ++c) {
                const float* xs = xg + c * HW;
                const float v00 = xs[o00], v01 = xs[o01];
                const float v10 = xs[o10], v11 = xs[o11];
                const float top = fmaf(wx, v01 - v00, v00);
                const float bot = fmaf(wx, v11 - v10, v10);
                og[c * OHW + oidx] = fmaf(wy, bot - top, top);
            }
        }
    }
}

extern "C" void kernel_launch(void* const* d_in, const int* in_sizes, int n_in,
                              void* d_out, int out_size, void* d_ws, size_t ws_size,
                              hipStream_t stream) {
    const float* x     = (const float*)d_in[0];
    const float* w_off = (const float*)d_in[1];
    const float* b_off = (const float*)d_in[2];
    float* out = (float*)d_out;
    (void)in_sizes; (void)n_in; (void)out_size; (void)d_ws; (void)ws_size;
    dysample_kernel<<<dim3(BB * TILES), dim3(256), 0, stream>>>(x, w_off, b_off, out);
}

// Round 3
// 382.769 us; speedup vs baseline: 1.1259x; 1.1259x over previous
//
#include <hip/hip_runtime.h>
#include <hip/hip_fp16.h>

// DySample fused kernel for MI355X (gfx950) — round 3 (r2 + compile fix).
// x: [16,64,128,128] f32, w_off: [32,64] f32, b_off: [32] f32
// out: [16,64,256,256] f32
//
// Grid = 2048 blocks: each (b, tile, g-pair). Twin blocks (g-pair 0/1) share
// the same 8x32 input tile; each computes only its 16 of 32 conv outputs
// (same total FLOPs), enabling 8 blocks/CU (100% wave occupancy, LDS 8 KB).
// Offsets stored in LDS as half2 (err ~1.5e-4 on coords, harmless vs 0.08).
// Phase 2: each thread handles 2 adjacent output pixels -> float2 NT stores
// (native clang vector type — HIP's float2 struct is rejected by the builtin).

namespace {
constexpr int CC = 64;
constexpr int HH = 128;
constexpr int WW = 128;
constexpr int HW = HH * WW;     // 16384
constexpr int OW = 2 * WW;      // 256
constexpr int OHW = 4 * HW;     // 65536
constexpr int TH = 8, TW = 32;  // input tile (256 px)
typedef float vfloat2 __attribute__((ext_vector_type(2)));
}

__global__ __launch_bounds__(256, 8)
void dysample_kernel(const float* __restrict__ x,
                     const float* __restrict__ w_off,
                     const float* __restrict__ b_off,
                     float* __restrict__ out) {
    __shared__ __half2 offh[8][256];   // 8 KB: (offx,offy) per local-q per pixel

    const int tid = threadIdx.x;
    const int gg   = blockIdx.x & 1;          // g-pair: g in {2gg, 2gg+1}
    const int tile = (blockIdx.x >> 1) & 63;
    const int b    = blockIdx.x >> 7;
    const int th0  = (tile >> 2) * TH;
    const int tw0  = (tile & 3) * TW;
    const int ty   = tid >> 5;                // [0,8)
    const int tx   = tid & 31;                // [0,32)
    const int h    = th0 + ty;
    const int w    = tw0 + tx;
    const int q0   = gg * 8;                  // first of 8 q-channels (x half)

    // ---------- Phase 1: 1x1 conv, 16 of 32 outputs at this thread's pixel ----
    float accx[8], accy[8];
#pragma unroll
    for (int j = 0; j < 8; ++j) {
        accx[j] = b_off[q0 + j];
        accy[j] = b_off[q0 + j + 16];
    }

    const float* xb = x + b * (CC * HW) + h * WW + w;
#pragma unroll
    for (int chunk = 0; chunk < 4; ++chunk) {
        float xv[16];
#pragma unroll
        for (int c = 0; c < 16; ++c) xv[c] = xb[(chunk * 16 + c) * HW];
#pragma unroll
        for (int j = 0; j < 8; ++j) {
            float ax = accx[j], ay = accy[j];
            const float* wx_ = w_off + (q0 + j) * 64 + chunk * 16;
            const float* wy_ = wx_ + 16 * 64;
#pragma unroll
            for (int c = 0; c < 16; ++c) ax = fmaf(xv[c], wx_[c], ax);
#pragma unroll
            for (int c = 0; c < 16; ++c) ay = fmaf(xv[c], wy_[c], ay);
            accx[j] = ax; accy[j] = ay;
        }
    }

#pragma unroll
    for (int j = 0; j < 8; ++j) {
        const int q = q0 + j, g = q >> 2, r1 = (q >> 1) & 1, r2 = q & 1;
        const float init = (((g & 1) ? r1 : r2) ? 0.25f : -0.25f);
        const float offx = fmaf(accx[j], 0.25f, init);
        const float offy = fmaf(accy[j], 0.25f, init);
        offh[j][tid] = __floats2half2_rn(offx, offy);
    }
    __syncthreads();

    // ---------- Phase 2: bilinear sampling; 2 output px (adjacent ox) / thread
    const int k   = tid & 31;                 // pair column [0,32)
    const float fw = (float)(tw0 + k);
#pragma unroll
    for (int gi = 0; gi < 2; ++gi) {
        const int g = gg * 2 + gi;
        const float* xg = x + (b * CC + g * 16) * HW;
        float* og = out + (size_t)(b * CC + g * 16) * OHW;
#pragma unroll
        for (int rep = 0; rep < 2; ++rep) {
            const int oy  = rep * 8 + (ty);   // [0,16) output row in tile
            const int jq  = gi * 4 + ((oy & 1) << 1);   // local q, r2=0
            const int pix = ((oy >> 1) << 5) | k;
            const float2 o0 = __half22float2(offh[jq][pix]);
            const float2 o1 = __half22float2(offh[jq + 1][pix]);
            const float fh = (float)(th0 + (oy >> 1));

            float ix0 = ((fw + 0.5f) + o0.x) - 0.5f;
            float iy0 = ((fh + 0.5f) + o0.y) - 0.5f;
            float ix1 = ((fw + 0.5f) + o1.x) - 0.5f;
            float iy1 = ((fh + 0.5f) + o1.y) - 0.5f;
            ix0 = fminf(fmaxf(ix0, 0.0f), 127.0f);
            iy0 = fminf(fmaxf(iy0, 0.0f), 127.0f);
            ix1 = fminf(fmaxf(ix1, 0.0f), 127.0f);
            iy1 = fminf(fmaxf(iy1, 0.0f), 127.0f);

            const float x0f0 = floorf(ix0), y0f0 = floorf(iy0);
            const float x0f1 = floorf(ix1), y0f1 = floorf(iy1);
            const float wx0 = ix0 - x0f0, wy0 = iy0 - y0f0;
            const float wx1 = ix1 - x0f1, wy1 = iy1 - y0f1;
            const int xa0 = (int)x0f0, ya0 = (int)y0f0;
            const int xa1 = (int)x0f1, ya1 = (int)y0f1;
            const int xb0 = min(xa0 + 1, WW - 1), yb0 = min(ya0 + 1, HH - 1);
            const int xb1 = min(xa1 + 1, WW - 1), yb1 = min(ya1 + 1, HH - 1);
            const int a00 = ya0 * WW + xa0, a01 = ya0 * WW + xb0;
            const int a10 = yb0 * WW + xa0, a11 = yb0 * WW + xb0;
            const int b00 = ya1 * WW + xa1, b01 = ya1 * WW + xb1;
            const int b10 = yb1 * WW + xa1, b11 = yb1 * WW + xb1;
            const int oidx = (th0 * 2 + oy) * OW + (tw0 * 2 + 2 * k);

#pragma unroll
            for (int c = 0; c < 16; ++c) {
                const float* xs = xg + c * HW;
                const float va00 = xs[a00], va01 = xs[a01];
                const float va10 = xs[a10], va11 = xs[a11];
                const float vb00 = xs[b00], vb01 = xs[b01];
                const float vb10 = xs[b10], vb11 = xs[b11];
                const float t0 = fmaf(wx0, va01 - va00, va00);
                const float u0 = fmaf(wx0, va11 - va10, va10);
                const float t1 = fmaf(wx1, vb01 - vb00, vb00);
                const float u1 = fmaf(wx1, vb11 - vb10, vb10);
                vfloat2 r;
                r.x = fmaf(wy0, u0 - t0, t0);
                r.y = fmaf(wy1, u1 - t1, t1);
                __builtin_nontemporal_store(r, (vfloat2*)(og + c * OHW + oidx));
            }
        }
    }
}

extern "C" void kernel_launch(void* const* d_in, const int* in_sizes, int n_in,
                              void* d_out, int out_size, void* d_ws, size_t ws_size,
                              hipStream_t stream) {
    const float* x     = (const float*)d_in[0];
    const float* w_off = (const float*)d_in[1];
    const float* b_off = (const float*)d_in[2];
    float* out = (float*)d_out;
    (void)in_sizes; (void)n_in; (void)out_size; (void)d_ws; (void)ws_size;
    dysample_kernel<<<dim3(16 * 64 * 2), dim3(256), 0, stream>>>(x, w_off, b_off, out);
}